// Round 3
// baseline (61.023 us; speedup 1.0000x reference)
//
#include <hip/hip_runtime.h>

// Problem constants (from reference setup_inputs):
//   logits: (N=4, C=19, H=512, W=1024) float32, target unused.
#define NCLS 19
#define NSMP 4
#define HW   (512 * 1024)
#define NSEG (NSMP * NCLS)   // 76 segments

// ws layout (floats): [0..76) = S1, [76..152) = S2, [152..228) = cnt
//
// Persistent main kernel: 512 blocks x 256 threads, 4 tiles per thread.
// Tile k of block b covers pixels [b*1024 + tid*4 .. +4) of SAMPLE k
// (512 tiles of 1024 px = exactly one sample plane), so every thread's
// 4 tiles sit at the same intra-sample offset in samples 0..3 and the
// LDS bin row for tile k is exactly segment row k*19+cls.
// Register double-buffer: while consuming tile k's channels, issue tile
// k+1's loads channel-by-channel -> continuous VMEM issue, no burst/drain.

__global__ __launch_bounds__(256) void cl_main(const float* __restrict__ logits,
                                               float* __restrict__ ws) {
    __shared__ float sb[3 * NSEG];   // [S1 | S2 | cnt] x (sample k * 19 + cls)
    const int tid = threadIdx.x;
    if (tid < 3 * NSEG) sb[tid] = 0.0f;
    __syncthreads();

    // intra-sample pixel offset for this thread (same for all 4 tiles)
    const size_t off  = (size_t)blockIdx.x * 1024 + (size_t)tid * 4;
    const float* base = logits + off;

    float4 va[NCLS], vb[NCLS];

    // prologue: issue tile 0 (sample 0) loads
    #pragma unroll
    for (int c = 0; c < NCLS; ++c)
        va[c] = *(const float4*)(base + (size_t)c * HW);

#define STEP(CUR, NXT, K, DOLOAD)                                              \
    do {                                                                       \
        float s1[4], s2[4], mv[4];                                             \
        int   mi[4];                                                           \
        _Pragma("unroll")                                                      \
        for (int c = 0; c < NCLS; ++c) {                                       \
            if (DOLOAD)                                                        \
                NXT[c] = *(const float4*)(base + ((size_t)((K) + 1) * NCLS + c) * HW); \
            const float a[4] = {CUR[c].x, CUR[c].y, CUR[c].z, CUR[c].w};       \
            _Pragma("unroll")                                                  \
            for (int j = 0; j < 4; ++j) {                                      \
                if (c == 0) {                                                  \
                    s1[j] = a[j]; s2[j] = a[j] * a[j];                         \
                    mv[j] = a[j]; mi[j] = 0;                                   \
                } else {                                                       \
                    s1[j] += a[j];                                             \
                    s2[j]  = fmaf(a[j], a[j], s2[j]);                          \
                    if (a[j] > mv[j]) { mv[j] = a[j]; mi[j] = c; }             \
                }                                                              \
            }                                                                  \
        }                                                                      \
        _Pragma("unroll")                                                      \
        for (int j = 0; j < 4; ++j) {                                          \
            atomicAdd(&sb[0 * NSEG + (K) * NCLS + mi[j]], s1[j]);              \
            atomicAdd(&sb[1 * NSEG + (K) * NCLS + mi[j]], s2[j]);              \
            atomicAdd(&sb[2 * NSEG + (K) * NCLS + mi[j]], 1.0f);               \
        }                                                                      \
        /* bound load-hoisting to one-tile lookahead */                        \
        asm volatile("" ::: "memory");                                         \
    } while (0)

    STEP(va, vb, 0, true);   // consume sample 0, issue sample 1
    STEP(vb, va, 1, true);   // consume sample 1, issue sample 2
    STEP(va, vb, 2, true);   // consume sample 2, issue sample 3
    STEP(vb, va, 3, false);  // consume sample 3
#undef STEP

    __syncthreads();
    if (tid < NSEG) {
        atomicAdd(&ws[tid],            sb[tid]);
        atomicAdd(&ws[NSEG + tid],     sb[NSEG + tid]);
        atomicAdd(&ws[2 * NSEG + tid], sb[2 * NSEG + tid]);
    }
}

__global__ void cl_final(const float* __restrict__ ws, float* __restrict__ out) {
    __shared__ float red[128];
    const int i = threadIdx.x;
    float v = 0.0f;
    if (i < NSEG) {
        const float S1  = ws[i];
        const float S2  = ws[NSEG + i];
        const float cnt = ws[2 * NSEG + i];
        const float K   = fmaxf(cnt, 1.0f) * (float)NCLS;
        const float sq  = fmaxf(S2 - S1 * S1 / K, 0.0f);
        v = (cnt > 0.0f) ? sqrtf(sq) : 0.0f;
    }
    red[i] = v;
    __syncthreads();
    #pragma unroll
    for (int s = 64; s > 0; s >>= 1) {
        if (i < s) red[i] += red[i + s];
        __syncthreads();
    }
    if (i == 0) out[0] = red[0] / (float)NSMP;
}

extern "C" void kernel_launch(void* const* d_in, const int* in_sizes, int n_in,
                              void* d_out, int out_size, void* d_ws, size_t ws_size,
                              hipStream_t stream) {
    const float* logits = (const float*)d_in[0];
    // d_in[1] (target) is unused by the reference computation.
    float* ws  = (float*)d_ws;
    float* out = (float*)d_out;

    hipMemsetAsync(ws, 0, 3 * NSEG * sizeof(float), stream);
    cl_main<<<512, 256, 0, stream>>>(logits, ws);
    cl_final<<<1, 128, 0, stream>>>(ws, out);
}